// Round 9
// baseline (218.566 us; speedup 1.0000x reference)
//
#include <hip/hip_runtime.h>
#include <hip/hip_fp16.h>

#define N_NODES 100000
#define N_EDGES 1600000
#define D_IN 32
#define D_HID 64
#define D_OUT 32
#define CAP 48          // padded CSR row capacity; P(deg>48|Poisson(16)) < 1e-11/node
#define PGROUPS 500     // dst-space partitions; one sort block per group
#define PGSIZE 200      // nodes per group (500*200 = 100000 exactly)
#define PBINCAP 3840    // per-group edge bin capacity; Poisson(3200) +11 sigma
#define PTILE 2048      // edges per partition block (256 thr * 8)

// ---------------- phase 1: single-pass LDS-binned edge partition (500 bins) ----------------
// 782 blocks (3/CU; was 196 = 0.77/CU -> underutilized).
__global__ void __launch_bounds__(256) partition_kernel(
    const int* __restrict__ src, const int* __restrict__ dst,
    int* __restrict__ gcur, int2* __restrict__ bins, int E) {
    __shared__ int lcnt[PGROUPS];
    __shared__ int lbase[PGROUPS];
    for (int t = threadIdx.x; t < PGROUPS; t += 256) lcnt[t] = 0;
    __syncthreads();
    int base = blockIdx.x * PTILE + threadIdx.x * 8;
    int s[8], d[8], g[8], p[8];
    int nloc = 0;
    if (base < E) nloc = min(8, E - base);
    if (nloc == 8) {
#pragma unroll
        for (int q = 0; q < 2; ++q) {
            int4 sv = *(const int4*)(src + base + 4 * q);
            int4 dv = *(const int4*)(dst + base + 4 * q);
            s[4*q+0] = sv.x; s[4*q+1] = sv.y; s[4*q+2] = sv.z; s[4*q+3] = sv.w;
            d[4*q+0] = dv.x; d[4*q+1] = dv.y; d[4*q+2] = dv.z; d[4*q+3] = dv.w;
        }
#pragma unroll
        for (int k = 0; k < 8; ++k) {
            g[k] = d[k] / PGSIZE;
            p[k] = atomicAdd(&lcnt[g[k]], 1);   // LDS atomic
        }
    } else {
        for (int k = 0; k < nloc; ++k) { s[k] = src[base + k]; d[k] = dst[base + k]; }
        for (int k = 0; k < nloc; ++k) {
            g[k] = d[k] / PGSIZE;
            p[k] = atomicAdd(&lcnt[g[k]], 1);
        }
    }
    __syncthreads();
    for (int t = threadIdx.x; t < PGROUPS; t += 256)
        lbase[t] = lcnt[t] ? atomicAdd(&gcur[t], lcnt[t]) : 0;
    __syncthreads();
    if (nloc == 8) {
#pragma unroll
        for (int k = 0; k < 8; ++k) {
            int idx = lbase[g[k]] + p[k];
            if (idx < PBINCAP) bins[(size_t)g[k] * PBINCAP + idx] = make_int2(s[k], d[k]);
        }
    } else {
        for (int k = 0; k < nloc; ++k) {
            int idx = lbase[g[k]] + p[k];
            if (idx < PBINCAP) bins[(size_t)g[k] * PBINCAP + idx] = make_int2(s[k], d[k]);
        }
    }
}

// ---------------- phase 2: per-group CSR build (LDS counting) + fused xd scale ----------------
// 500 blocks (2/CU; was 250 = 1/CU). One block owns one 200-node group.
__global__ void __launch_bounds__(256) sort_scale_kernel(
    const int2* __restrict__ bins, const int* __restrict__ gcur,
    const float* __restrict__ x,
    int* __restrict__ cnt, int* __restrict__ csr, __half* __restrict__ xd) {
    __shared__ int lcnt[PGSIZE];
    int g = blockIdx.x;
    for (int t = threadIdx.x; t < PGSIZE; t += 256) lcnt[t] = 0;
    __syncthreads();
    int n = gcur[g];
    if (n > PBINCAP) n = PBINCAP;
    const int2* bin = bins + (size_t)g * PBINCAP;
    int lo = g * PGSIZE;
    int i = threadIdx.x;
    for (; i + 768 < n; i += 1024) {
        int2 e0 = bin[i];
        int2 e1 = bin[i + 256];
        int2 e2 = bin[i + 512];
        int2 e3 = bin[i + 768];
        int p0 = atomicAdd(&lcnt[e0.y - lo], 1);
        int p1 = atomicAdd(&lcnt[e1.y - lo], 1);
        int p2 = atomicAdd(&lcnt[e2.y - lo], 1);
        int p3 = atomicAdd(&lcnt[e3.y - lo], 1);
        if (p0 < CAP) csr[(size_t)e0.y * CAP + p0] = e0.x;
        if (p1 < CAP) csr[(size_t)e1.y * CAP + p1] = e1.x;
        if (p2 < CAP) csr[(size_t)e2.y * CAP + p2] = e2.x;
        if (p3 < CAP) csr[(size_t)e3.y * CAP + p3] = e3.x;
    }
    for (; i < n; i += 256) {
        int2 e = bin[i];
        int pos = atomicAdd(&lcnt[e.y - lo], 1);
        if (pos < CAP) csr[(size_t)e.y * CAP + pos] = e.x;
    }
    __syncthreads();
    for (int t = threadIdx.x; t < PGSIZE; t += 256) cnt[lo + t] = lcnt[t];
    // fused scale: 8 lanes/node, row-major xd[n][32]
    for (int u = threadIdx.x; u < PGSIZE * 8; u += 256) {
        int t = u >> 3, c = (u & 7) * 4;
        int node = lo + t;
        float di = rsqrtf((float)lcnt[t] + 1.0f);
        float4 v = *(const float4*)(x + (size_t)node * D_IN + c);
        __half2 h0 = __floats2half2_rn(v.x * di, v.y * di);
        __half2 h1 = __floats2half2_rn(v.z * di, v.w * di);
        float2 packed = make_float2(*(float*)&h0, *(float*)&h1);
        *(float2*)(xd + (size_t)node * D_IN + c) = packed;
    }
}

#define ACC2(acc, raw) do { __half2* hp_ = (__half2*)&(raw); \
    float2 g0_ = __half22float2(hp_[0]), g1_ = __half22float2(hp_[1]); \
    (acc).x += g0_.x; (acc).y += g0_.y; (acc).z += g1_.x; (acc).w += g1_.y; } while (0)

#define GLD(tbl, idx, rv) float2 rv = *(const float2*)((tbl) + (size_t)(idx) * D_IN + c)

// ---------------- fused layer-1 aggregation + both dense GEMMs ----------------
// 32 nodes/block, 8 thr/node, 16-wide gather batch. ax stays in REGISTERS:
// GEMM1 shfl-broadcasts ax across the node's 8 lanes (no axs LDS buffer).
// LDS = W1s(8K)+W2s(8K)+b1s+h1s(8.3K) = 24.4KB -> 6 blocks/CU (was 5 at 29.7KB).
__global__ void __launch_bounds__(256, 6) agg_mlp_kernel(
    const int* __restrict__ cnt, const int* __restrict__ csr,
    const __half* __restrict__ xd,
    const float* __restrict__ W1, const float* __restrict__ b1,
    const float* __restrict__ W2, __half* __restrict__ g2, int N) {
    __shared__ float W1s[D_IN * D_HID];    // 8 KB [k][j] j=64
    __shared__ float W2s[D_HID * D_OUT];   // 8 KB [k][j] j=32
    __shared__ float b1s[D_HID];
    __shared__ float h1s[32][65];          // stride 65: 2-way max (free)
    for (int t = threadIdx.x; t < D_IN * D_HID; t += 256) W1s[t] = W1[t];
    for (int t = threadIdx.x; t < D_HID * D_OUT; t += 256) W2s[t] = W2[t];
    if (threadIdx.x < D_HID) b1s[threadIdx.x] = b1[threadIdx.x];

    int nl = threadIdx.x >> 3;   // node within block
    int l8 = threadIdx.x & 7;
    int n = blockIdx.x * 32 + nl;          // exact: N % 32 == 0
    int c = l8 * 4;
    int cn = cnt[n];
    int m = cn < CAP ? cn : CAP;
    float di = rsqrtf((float)cn + 1.0f);

    float4 acc, accB = make_float4(0.f, 0.f, 0.f, 0.f);
    {
        float2 raw = *(const float2*)(xd + (size_t)n * D_IN + c);
        __half2* hp = (__half2*)&raw;
        float2 f0 = __half22float2(hp[0]), f1 = __half22float2(hp[1]);
        acc = make_float4(f0.x, f0.y, f1.x, f1.y);
    }
    const int4* row4 = (const int4*)(csr + (size_t)n * CAP);
    int i = 0;
    for (; i + 16 <= m; i += 16) {
        int4 sa = row4[(i >> 2) + 0];
        int4 sb = row4[(i >> 2) + 1];
        int4 sc = row4[(i >> 2) + 2];
        int4 sd = row4[(i >> 2) + 3];
        GLD(xd, sa.x, r0);  GLD(xd, sa.y, r1);  GLD(xd, sa.z, r2);  GLD(xd, sa.w, r3);
        GLD(xd, sb.x, r4);  GLD(xd, sb.y, r5);  GLD(xd, sb.z, r6);  GLD(xd, sb.w, r7);
        GLD(xd, sc.x, r8);  GLD(xd, sc.y, r9);  GLD(xd, sc.z, r10); GLD(xd, sc.w, r11);
        GLD(xd, sd.x, r12); GLD(xd, sd.y, r13); GLD(xd, sd.z, r14); GLD(xd, sd.w, r15);
        ACC2(acc, r0);  ACC2(accB, r1);  ACC2(acc, r2);  ACC2(accB, r3);
        ACC2(acc, r4);  ACC2(accB, r5);  ACC2(acc, r6);  ACC2(accB, r7);
        ACC2(acc, r8);  ACC2(accB, r9);  ACC2(acc, r10); ACC2(accB, r11);
        ACC2(acc, r12); ACC2(accB, r13); ACC2(acc, r14); ACC2(accB, r15);
    }
    for (; i + 8 <= m; i += 8) {
        int4 sa = row4[(i >> 2) + 0];
        int4 sb = row4[(i >> 2) + 1];
        GLD(xd, sa.x, r0); GLD(xd, sa.y, r1); GLD(xd, sa.z, r2); GLD(xd, sa.w, r3);
        GLD(xd, sb.x, r4); GLD(xd, sb.y, r5); GLD(xd, sb.z, r6); GLD(xd, sb.w, r7);
        ACC2(acc, r0); ACC2(accB, r1); ACC2(acc, r2); ACC2(accB, r3);
        ACC2(acc, r4); ACC2(accB, r5); ACC2(acc, r6); ACC2(accB, r7);
    }
    for (; i + 4 <= m; i += 4) {
        int4 s4 = row4[i >> 2];
        GLD(xd, s4.x, r0); GLD(xd, s4.y, r1); GLD(xd, s4.z, r2); GLD(xd, s4.w, r3);
        ACC2(acc, r0); ACC2(accB, r1); ACC2(acc, r2); ACC2(accB, r3);
    }
    const int* row = csr + (size_t)n * CAP;
    for (; i < m; ++i) {
        float2 raw = *(const float2*)(xd + (size_t)row[i] * D_IN + c);
        ACC2(acc, raw);
    }
    // ax = di*(self + sum), kept in registers (this lane owns k = c..c+3)
    float4 ax = make_float4(di * (acc.x + accB.x), di * (acc.y + accB.y),
                            di * (acc.z + accB.z), di * (acc.w + accB.w));
    __syncthreads();   // weights + b1s staged

    // GEMM1: h1[j] for j = l8*8..+7; broadcast ax quads across the node's 8 lanes.
    // k-order identical to the previous sequential k=0..31 loop (same numerics).
    float h1v[8];
#pragma unroll
    for (int jj = 0; jj < 8; ++jj) h1v[jj] = b1s[l8 * 8 + jj];
#pragma unroll
    for (int r = 0; r < 8; ++r) {
        float a0 = __shfl(ax.x, r, 8);
        float a1 = __shfl(ax.y, r, 8);
        float a2 = __shfl(ax.z, r, 8);
        float a3 = __shfl(ax.w, r, 8);
        int k0 = r * 4;
#pragma unroll
        for (int jj = 0; jj < 8; ++jj) {
            int j = l8 * 8 + jj;
            h1v[jj] += a0 * W1s[(k0 + 0) * D_HID + j] + a1 * W1s[(k0 + 1) * D_HID + j]
                     + a2 * W1s[(k0 + 2) * D_HID + j] + a3 * W1s[(k0 + 3) * D_HID + j];
        }
    }
#pragma unroll
    for (int jj = 0; jj < 8; ++jj) h1s[nl][l8 * 8 + jj] = fmaxf(h1v[jj], 0.f);
    __syncthreads();

    // GEMM2: g2[c..c+3]
    float o0 = 0.f, o1 = 0.f, o2 = 0.f, o3 = 0.f;
#pragma unroll
    for (int k = 0; k < D_HID; ++k) {
        float hk = h1s[nl][k];
        o0 += hk * W2s[k * D_OUT + c + 0];
        o1 += hk * W2s[k * D_OUT + c + 1];
        o2 += hk * W2s[k * D_OUT + c + 2];
        o3 += hk * W2s[k * D_OUT + c + 3];
    }
    __half2 p0 = __floats2half2_rn(di * o0, di * o1);
    __half2 p1 = __floats2half2_rn(di * o2, di * o3);
    float2 packed = make_float2(*(float*)&p0, *(float*)&p1);
    *(float2*)(g2 + (size_t)n * D_OUT + c) = packed;
}

// ---------------- agg2: h2 = half(dinv*(g2[n]+sum g2[s]) + b2), 8 thr/node, 16-wide ----------------
__global__ void __launch_bounds__(256) agg2_kernel(
    const int* __restrict__ cnt, const int* __restrict__ csr,
    const __half* __restrict__ G, const float* __restrict__ b,
    __half* __restrict__ OUT, int N) {
    int gid = blockIdx.x * 256 + threadIdx.x;
    int n = gid >> 3;            // exact: N*8 % 256 == 0
    int c = (gid & 7) * 4;
    int cn = cnt[n];
    int m = cn < CAP ? cn : CAP;
    float4 acc, accB = make_float4(0.f, 0.f, 0.f, 0.f);
    {
        float2 raw = *(const float2*)(G + (size_t)n * D_OUT + c);
        __half2* hp = (__half2*)&raw;
        float2 f0 = __half22float2(hp[0]), f1 = __half22float2(hp[1]);
        acc = make_float4(f0.x, f0.y, f1.x, f1.y);
    }
    const int4* row4 = (const int4*)(csr + (size_t)n * CAP);
    int i = 0;
    for (; i + 16 <= m; i += 16) {
        int4 sa = row4[(i >> 2) + 0];
        int4 sb = row4[(i >> 2) + 1];
        int4 sc = row4[(i >> 2) + 2];
        int4 sd = row4[(i >> 2) + 3];
        GLD(G, sa.x, r0);  GLD(G, sa.y, r1);  GLD(G, sa.z, r2);  GLD(G, sa.w, r3);
        GLD(G, sb.x, r4);  GLD(G, sb.y, r5);  GLD(G, sb.z, r6);  GLD(G, sb.w, r7);
        GLD(G, sc.x, r8);  GLD(G, sc.y, r9);  GLD(G, sc.z, r10); GLD(G, sc.w, r11);
        GLD(G, sd.x, r12); GLD(G, sd.y, r13); GLD(G, sd.z, r14); GLD(G, sd.w, r15);
        ACC2(acc, r0);  ACC2(accB, r1);  ACC2(acc, r2);  ACC2(accB, r3);
        ACC2(acc, r4);  ACC2(accB, r5);  ACC2(acc, r6);  ACC2(accB, r7);
        ACC2(acc, r8);  ACC2(accB, r9);  ACC2(acc, r10); ACC2(accB, r11);
        ACC2(acc, r12); ACC2(accB, r13); ACC2(acc, r14); ACC2(accB, r15);
    }
    for (; i + 8 <= m; i += 8) {
        int4 sa = row4[(i >> 2) + 0];
        int4 sb = row4[(i >> 2) + 1];
        GLD(G, sa.x, r0); GLD(G, sa.y, r1); GLD(G, sa.z, r2); GLD(G, sa.w, r3);
        GLD(G, sb.x, r4); GLD(G, sb.y, r5); GLD(G, sb.z, r6); GLD(G, sb.w, r7);
        ACC2(acc, r0); ACC2(accB, r1); ACC2(acc, r2); ACC2(accB, r3);
        ACC2(acc, r4); ACC2(accB, r5); ACC2(acc, r6); ACC2(accB, r7);
    }
    for (; i + 4 <= m; i += 4) {
        int4 s4 = row4[i >> 2];
        GLD(G, s4.x, r0); GLD(G, s4.y, r1); GLD(G, s4.z, r2); GLD(G, s4.w, r3);
        ACC2(acc, r0); ACC2(accB, r1); ACC2(acc, r2); ACC2(accB, r3);
    }
    const int* row = csr + (size_t)n * CAP;
    for (; i < m; ++i) {
        float2 raw = *(const float2*)(G + (size_t)row[i] * D_OUT + c);
        ACC2(acc, raw);
    }
    float di = rsqrtf((float)cn + 1.0f);
    __half2 h0 = __floats2half2_rn(di * (acc.x + accB.x) + b[c + 0],
                                   di * (acc.y + accB.y) + b[c + 1]);
    __half2 h1 = __floats2half2_rn(di * (acc.z + accB.z) + b[c + 2],
                                   di * (acc.w + accB.w) + b[c + 3]);
    float2 packed = make_float2(*(float*)&h0, *(float*)&h1);
    *(float2*)(OUT + (size_t)n * D_OUT + c) = packed;
}

// ---------------- logits: 4 thr/edge (at random-line fill floor), H fp16 [N,32] ----------------
__global__ void logits_kernel(const int* __restrict__ src, const int* __restrict__ dst,
                              const __half* __restrict__ H, float* __restrict__ out, int E) {
    long long gid = (long long)blockIdx.x * blockDim.x + threadIdx.x;
    int e = (int)(gid >> 2);
    int c = ((int)gid & 3) * 8;
    if (e >= E) return;
    int s = src[e], d = dst[e];
    float4 ra = *(const float4*)(H + (long long)s * D_OUT + c);
    float4 rb = *(const float4*)(H + (long long)d * D_OUT + c);
    __half2* pa = (__half2*)&ra;
    __half2* pb = (__half2*)&rb;
    float p = 0.f;
#pragma unroll
    for (int k = 0; k < 4; ++k) {
        float2 fa = __half22float2(pa[k]);
        float2 fb = __half22float2(pb[k]);
        p += fa.x * fb.x + fa.y * fb.y;
    }
    p += __shfl_xor(p, 1);
    p += __shfl_xor(p, 2);
    if ((gid & 3) == 0) out[e] = p;
}

extern "C" void kernel_launch(void* const* d_in, const int* in_sizes, int n_in,
                              void* d_out, int out_size, void* d_ws, size_t ws_size,
                              hipStream_t stream) {
    const float* x  = (const float*)d_in[0];
    const int* edge = (const int*)d_in[1];  // [2, E]: row0 = src, row1 = dst
    const float* W1 = (const float*)d_in[2];
    const float* b1 = (const float*)d_in[3];
    const float* W2 = (const float*)d_in[4];
    const float* b2 = (const float*)d_in[5];
    float* out = (float*)d_out;

    const int* src = edge;
    const int* dst = edge + N_EDGES;

    // workspace layout (~41.4 MB peak, aliased):
    //   gcur(512i) | cnt(N) | csr(19.2M) | bins(15.36M) | xd(6.4M)
    //   g2h(6.4M) + h2h(6.4M) alias bins (bins dead after sort_scale; 12.8 <= 15.36)
    char* ws = (char*)d_ws;
    int*    gcur = (int*)ws;                                   // 512 ints (zeroed)
    int*    cnt  = gcur + 512;                                 // N ints
    int*    csr  = cnt + N_NODES;                              // N*CAP ints (19.2 MB)
    int2*   bins = (int2*)(csr + (size_t)N_NODES * CAP);       // 500*3840*8 = 15.36 MB
    __half* xd   = (__half*)(bins + (size_t)PGROUPS * PBINCAP);// N*32 halves (6.4 MB)
    __half* g2h  = (__half*)bins;                              // alias: bins dead after sort
    __half* h2h  = g2h + (size_t)N_NODES * D_OUT;              // alias: still inside bins

    hipMemsetAsync(gcur, 0, 512 * sizeof(int), stream);

    // one coalesced edge scan -> 500 dst-range bins (782 blocks)
    partition_kernel<<<(N_EDGES + PTILE - 1) / PTILE, 256, 0, stream>>>(src, dst, gcur, bins, N_EDGES);

    // per-group CSR build (LDS counting, no global atomics) + fused xd = half(x*dinv)
    sort_scale_kernel<<<PGROUPS, 256, 0, stream>>>(bins, gcur, x, cnt, csr, xd);

    // fused: ax = dinv*(xd[n]+sum xd[s]); h1 = relu(ax@W1+b1); g2 = half(dinv*(h1@W2))
    agg_mlp_kernel<<<N_NODES / 32, 256, 0, stream>>>(cnt, csr, xd, W1, b1, W2, g2h, N_NODES);

    // h2 = half(dinv*(g2[n]+sum g2[s]) + b2)
    agg2_kernel<<<(N_NODES * 8) / 256, 256, 0, stream>>>(cnt, csr, g2h, b2, h2h, N_NODES);

    // per-edge logits
    logits_kernel<<<(N_EDGES * 4) / 256, 256, 0, stream>>>(src, dst, h2h, out, N_EDGES);
}

// Round 10
// 201.480 us; speedup vs baseline: 1.0848x; 1.0848x over previous
//
#include <hip/hip_runtime.h>
#include <hip/hip_fp16.h>

#define N_NODES 100000
#define N_EDGES 1600000
#define D_IN 32
#define D_HID 64
#define D_OUT 32
#define CAP 48          // padded CSR row capacity; P(deg>48|Poisson(16)) < 1e-11/node
#define PGROUPS 250     // dst-space partitions; one sort block per group
#define PGSIZE 400      // nodes per group (250*400 = 100000 exactly)
#define PBINCAP 7200    // per-group edge bin capacity; mean 6400, sigma ~80 -> +10 sigma
#define PTILE 8192      // edges per partition block (512 thr * 16) -> ~33 edges/bin/block

// ---------------- phase 1: single-pass LDS-binned edge partition (250 bins) ----------------
// R8 config: 196 blocks, 8192-edge tiles. Fewer blocks but ~264B contiguous bin writes;
// R9's 2048-tile variant fragmented bin stores to ~16-32B and cost +13us. Write
// granularity beats occupancy here.
__global__ void __launch_bounds__(512) partition_kernel(
    const int* __restrict__ src, const int* __restrict__ dst,
    int* __restrict__ gcur, int2* __restrict__ bins, int E) {
    __shared__ int lcnt[PGROUPS];
    __shared__ int lbase[PGROUPS];
    for (int t = threadIdx.x; t < PGROUPS; t += 512) lcnt[t] = 0;
    __syncthreads();
    int base = blockIdx.x * PTILE + threadIdx.x * 16;
    int s[16], d[16], g[16], p[16];
    int nloc = 0;
    if (base < E) nloc = min(16, E - base);
    if (nloc == 16) {
#pragma unroll
        for (int q = 0; q < 4; ++q) {
            int4 sv = *(const int4*)(src + base + 4 * q);
            int4 dv = *(const int4*)(dst + base + 4 * q);
            s[4*q+0] = sv.x; s[4*q+1] = sv.y; s[4*q+2] = sv.z; s[4*q+3] = sv.w;
            d[4*q+0] = dv.x; d[4*q+1] = dv.y; d[4*q+2] = dv.z; d[4*q+3] = dv.w;
        }
#pragma unroll
        for (int k = 0; k < 16; ++k) {
            g[k] = d[k] / PGSIZE;
            p[k] = atomicAdd(&lcnt[g[k]], 1);   // LDS atomic
        }
    } else {
        for (int k = 0; k < nloc; ++k) { s[k] = src[base + k]; d[k] = dst[base + k]; }
        for (int k = 0; k < nloc; ++k) {
            g[k] = d[k] / PGSIZE;
            p[k] = atomicAdd(&lcnt[g[k]], 1);
        }
    }
    __syncthreads();
    for (int t = threadIdx.x; t < PGROUPS; t += 512)
        lbase[t] = lcnt[t] ? atomicAdd(&gcur[t], lcnt[t]) : 0;
    __syncthreads();
    if (nloc == 16) {
#pragma unroll
        for (int k = 0; k < 16; ++k) {
            int idx = lbase[g[k]] + p[k];
            if (idx < PBINCAP) bins[(size_t)g[k] * PBINCAP + idx] = make_int2(s[k], d[k]);
        }
    } else {
        for (int k = 0; k < nloc; ++k) {
            int idx = lbase[g[k]] + p[k];
            if (idx < PBINCAP) bins[(size_t)g[k] * PBINCAP + idx] = make_int2(s[k], d[k]);
        }
    }
}

// ---------------- phase 2: per-group CSR build (LDS counting) + fused xd scale ----------------
// One block owns one 400-node group: LDS-atomic insert positions (no global atomics).
// Tail reuses the LDS histogram to write cnt AND xd = half(x*rsqrt(cnt+1)) row-major.
__global__ void __launch_bounds__(256) sort_scale_kernel(
    const int2* __restrict__ bins, const int* __restrict__ gcur,
    const float* __restrict__ x,
    int* __restrict__ cnt, int* __restrict__ csr, __half* __restrict__ xd) {
    __shared__ int lcnt[PGSIZE];
    int g = blockIdx.x;
    for (int t = threadIdx.x; t < PGSIZE; t += 256) lcnt[t] = 0;
    __syncthreads();
    int n = gcur[g];
    if (n > PBINCAP) n = PBINCAP;
    const int2* bin = bins + (size_t)g * PBINCAP;
    int lo = g * PGSIZE;
    int i = threadIdx.x;
    for (; i + 768 < n; i += 1024) {
        int2 e0 = bin[i];
        int2 e1 = bin[i + 256];
        int2 e2 = bin[i + 512];
        int2 e3 = bin[i + 768];
        int p0 = atomicAdd(&lcnt[e0.y - lo], 1);
        int p1 = atomicAdd(&lcnt[e1.y - lo], 1);
        int p2 = atomicAdd(&lcnt[e2.y - lo], 1);
        int p3 = atomicAdd(&lcnt[e3.y - lo], 1);
        if (p0 < CAP) csr[(size_t)e0.y * CAP + p0] = e0.x;
        if (p1 < CAP) csr[(size_t)e1.y * CAP + p1] = e1.x;
        if (p2 < CAP) csr[(size_t)e2.y * CAP + p2] = e2.x;
        if (p3 < CAP) csr[(size_t)e3.y * CAP + p3] = e3.x;
    }
    for (; i < n; i += 256) {
        int2 e = bin[i];
        int pos = atomicAdd(&lcnt[e.y - lo], 1);
        if (pos < CAP) csr[(size_t)e.y * CAP + pos] = e.x;
    }
    __syncthreads();
    for (int t = threadIdx.x; t < PGSIZE; t += 256) cnt[lo + t] = lcnt[t];
    // fused scale: 8 lanes/node, row-major xd[n][32]
    for (int u = threadIdx.x; u < PGSIZE * 8; u += 256) {
        int t = u >> 3, c = (u & 7) * 4;
        int node = lo + t;
        float di = rsqrtf((float)lcnt[t] + 1.0f);
        float4 v = *(const float4*)(x + (size_t)node * D_IN + c);
        __half2 h0 = __floats2half2_rn(v.x * di, v.y * di);
        __half2 h1 = __floats2half2_rn(v.z * di, v.w * di);
        float2 packed = make_float2(*(float*)&h0, *(float*)&h1);
        *(float2*)(xd + (size_t)node * D_IN + c) = packed;
    }
}

#define ACC2(acc, raw) do { __half2* hp_ = (__half2*)&(raw); \
    float2 g0_ = __half22float2(hp_[0]), g1_ = __half22float2(hp_[1]); \
    (acc).x += g0_.x; (acc).y += g0_.y; (acc).z += g1_.x; (acc).w += g1_.y; } while (0)

#define GLD(tbl, idx, rv) float2 rv = *(const float2*)((tbl) + (size_t)(idx) * D_IN + c)

// ---------------- fused layer-1 aggregation + both dense GEMMs (R9-proven) ----------------
// 32 nodes/block, 8 thr/node, 16-wide gather batch. ax stays in REGISTERS:
// GEMM1 shfl-broadcasts ax across the node's 8 lanes (no axs LDS buffer).
// LDS = 24.4KB; measured occupancy 50%, 47us, VALUBusy 36% (R9).
__global__ void __launch_bounds__(256, 6) agg_mlp_kernel(
    const int* __restrict__ cnt, const int* __restrict__ csr,
    const __half* __restrict__ xd,
    const float* __restrict__ W1, const float* __restrict__ b1,
    const float* __restrict__ W2, __half* __restrict__ g2, int N) {
    __shared__ float W1s[D_IN * D_HID];    // 8 KB [k][j] j=64
    __shared__ float W2s[D_HID * D_OUT];   // 8 KB [k][j] j=32
    __shared__ float b1s[D_HID];
    __shared__ float h1s[32][65];          // stride 65: 2-way max (free)
    for (int t = threadIdx.x; t < D_IN * D_HID; t += 256) W1s[t] = W1[t];
    for (int t = threadIdx.x; t < D_HID * D_OUT; t += 256) W2s[t] = W2[t];
    if (threadIdx.x < D_HID) b1s[threadIdx.x] = b1[threadIdx.x];

    int nl = threadIdx.x >> 3;   // node within block
    int l8 = threadIdx.x & 7;
    int n = blockIdx.x * 32 + nl;          // exact: N % 32 == 0
    int c = l8 * 4;
    int cn = cnt[n];
    int m = cn < CAP ? cn : CAP;
    float di = rsqrtf((float)cn + 1.0f);

    float4 acc, accB = make_float4(0.f, 0.f, 0.f, 0.f);
    {
        float2 raw = *(const float2*)(xd + (size_t)n * D_IN + c);
        __half2* hp = (__half2*)&raw;
        float2 f0 = __half22float2(hp[0]), f1 = __half22float2(hp[1]);
        acc = make_float4(f0.x, f0.y, f1.x, f1.y);
    }
    const int4* row4 = (const int4*)(csr + (size_t)n * CAP);
    int i = 0;
    for (; i + 16 <= m; i += 16) {
        int4 sa = row4[(i >> 2) + 0];
        int4 sb = row4[(i >> 2) + 1];
        int4 sc = row4[(i >> 2) + 2];
        int4 sd = row4[(i >> 2) + 3];
        GLD(xd, sa.x, r0);  GLD(xd, sa.y, r1);  GLD(xd, sa.z, r2);  GLD(xd, sa.w, r3);
        GLD(xd, sb.x, r4);  GLD(xd, sb.y, r5);  GLD(xd, sb.z, r6);  GLD(xd, sb.w, r7);
        GLD(xd, sc.x, r8);  GLD(xd, sc.y, r9);  GLD(xd, sc.z, r10); GLD(xd, sc.w, r11);
        GLD(xd, sd.x, r12); GLD(xd, sd.y, r13); GLD(xd, sd.z, r14); GLD(xd, sd.w, r15);
        ACC2(acc, r0);  ACC2(accB, r1);  ACC2(acc, r2);  ACC2(accB, r3);
        ACC2(acc, r4);  ACC2(accB, r5);  ACC2(acc, r6);  ACC2(accB, r7);
        ACC2(acc, r8);  ACC2(accB, r9);  ACC2(acc, r10); ACC2(accB, r11);
        ACC2(acc, r12); ACC2(accB, r13); ACC2(acc, r14); ACC2(accB, r15);
    }
    for (; i + 8 <= m; i += 8) {
        int4 sa = row4[(i >> 2) + 0];
        int4 sb = row4[(i >> 2) + 1];
        GLD(xd, sa.x, r0); GLD(xd, sa.y, r1); GLD(xd, sa.z, r2); GLD(xd, sa.w, r3);
        GLD(xd, sb.x, r4); GLD(xd, sb.y, r5); GLD(xd, sb.z, r6); GLD(xd, sb.w, r7);
        ACC2(acc, r0); ACC2(accB, r1); ACC2(acc, r2); ACC2(accB, r3);
        ACC2(acc, r4); ACC2(accB, r5); ACC2(acc, r6); ACC2(accB, r7);
    }
    for (; i + 4 <= m; i += 4) {
        int4 s4 = row4[i >> 2];
        GLD(xd, s4.x, r0); GLD(xd, s4.y, r1); GLD(xd, s4.z, r2); GLD(xd, s4.w, r3);
        ACC2(acc, r0); ACC2(accB, r1); ACC2(acc, r2); ACC2(accB, r3);
    }
    const int* row = csr + (size_t)n * CAP;
    for (; i < m; ++i) {
        float2 raw = *(const float2*)(xd + (size_t)row[i] * D_IN + c);
        ACC2(acc, raw);
    }
    // ax = di*(self + sum), kept in registers (this lane owns k = c..c+3)
    float4 ax = make_float4(di * (acc.x + accB.x), di * (acc.y + accB.y),
                            di * (acc.z + accB.z), di * (acc.w + accB.w));
    __syncthreads();   // weights + b1s staged

    // GEMM1: h1[j] for j = l8*8..+7; broadcast ax quads across the node's 8 lanes.
    float h1v[8];
#pragma unroll
    for (int jj = 0; jj < 8; ++jj) h1v[jj] = b1s[l8 * 8 + jj];
#pragma unroll
    for (int r = 0; r < 8; ++r) {
        float a0 = __shfl(ax.x, r, 8);
        float a1 = __shfl(ax.y, r, 8);
        float a2 = __shfl(ax.z, r, 8);
        float a3 = __shfl(ax.w, r, 8);
        int k0 = r * 4;
#pragma unroll
        for (int jj = 0; jj < 8; ++jj) {
            int j = l8 * 8 + jj;
            h1v[jj] += a0 * W1s[(k0 + 0) * D_HID + j] + a1 * W1s[(k0 + 1) * D_HID + j]
                     + a2 * W1s[(k0 + 2) * D_HID + j] + a3 * W1s[(k0 + 3) * D_HID + j];
        }
    }
#pragma unroll
    for (int jj = 0; jj < 8; ++jj) h1s[nl][l8 * 8 + jj] = fmaxf(h1v[jj], 0.f);
    __syncthreads();

    // GEMM2: g2[c..c+3]
    float o0 = 0.f, o1 = 0.f, o2 = 0.f, o3 = 0.f;
#pragma unroll
    for (int k = 0; k < D_HID; ++k) {
        float hk = h1s[nl][k];
        o0 += hk * W2s[k * D_OUT + c + 0];
        o1 += hk * W2s[k * D_OUT + c + 1];
        o2 += hk * W2s[k * D_OUT + c + 2];
        o3 += hk * W2s[k * D_OUT + c + 3];
    }
    __half2 p0 = __floats2half2_rn(di * o0, di * o1);
    __half2 p1 = __floats2half2_rn(di * o2, di * o3);
    float2 packed = make_float2(*(float*)&p0, *(float*)&p1);
    *(float2*)(g2 + (size_t)n * D_OUT + c) = packed;
}

// ---------------- agg2: h2 = half(dinv*(g2[n]+sum g2[s]) + b2), 8 thr/node, 16-wide ----------------
__global__ void __launch_bounds__(256) agg2_kernel(
    const int* __restrict__ cnt, const int* __restrict__ csr,
    const __half* __restrict__ G, const float* __restrict__ b,
    __half* __restrict__ OUT, int N) {
    int gid = blockIdx.x * 256 + threadIdx.x;
    int n = gid >> 3;            // exact: N*8 % 256 == 0
    int c = (gid & 7) * 4;
    int cn = cnt[n];
    int m = cn < CAP ? cn : CAP;
    float4 acc, accB = make_float4(0.f, 0.f, 0.f, 0.f);
    {
        float2 raw = *(const float2*)(G + (size_t)n * D_OUT + c);
        __half2* hp = (__half2*)&raw;
        float2 f0 = __half22float2(hp[0]), f1 = __half22float2(hp[1]);
        acc = make_float4(f0.x, f0.y, f1.x, f1.y);
    }
    const int4* row4 = (const int4*)(csr + (size_t)n * CAP);
    int i = 0;
    for (; i + 16 <= m; i += 16) {
        int4 sa = row4[(i >> 2) + 0];
        int4 sb = row4[(i >> 2) + 1];
        int4 sc = row4[(i >> 2) + 2];
        int4 sd = row4[(i >> 2) + 3];
        GLD(G, sa.x, r0);  GLD(G, sa.y, r1);  GLD(G, sa.z, r2);  GLD(G, sa.w, r3);
        GLD(G, sb.x, r4);  GLD(G, sb.y, r5);  GLD(G, sb.z, r6);  GLD(G, sb.w, r7);
        GLD(G, sc.x, r8);  GLD(G, sc.y, r9);  GLD(G, sc.z, r10); GLD(G, sc.w, r11);
        GLD(G, sd.x, r12); GLD(G, sd.y, r13); GLD(G, sd.z, r14); GLD(G, sd.w, r15);
        ACC2(acc, r0);  ACC2(accB, r1);  ACC2(acc, r2);  ACC2(accB, r3);
        ACC2(acc, r4);  ACC2(accB, r5);  ACC2(acc, r6);  ACC2(accB, r7);
        ACC2(acc, r8);  ACC2(accB, r9);  ACC2(acc, r10); ACC2(accB, r11);
        ACC2(acc, r12); ACC2(accB, r13); ACC2(acc, r14); ACC2(accB, r15);
    }
    for (; i + 8 <= m; i += 8) {
        int4 sa = row4[(i >> 2) + 0];
        int4 sb = row4[(i >> 2) + 1];
        GLD(G, sa.x, r0); GLD(G, sa.y, r1); GLD(G, sa.z, r2); GLD(G, sa.w, r3);
        GLD(G, sb.x, r4); GLD(G, sb.y, r5); GLD(G, sb.z, r6); GLD(G, sb.w, r7);
        ACC2(acc, r0); ACC2(accB, r1); ACC2(acc, r2); ACC2(accB, r3);
        ACC2(acc, r4); ACC2(accB, r5); ACC2(acc, r6); ACC2(accB, r7);
    }
    for (; i + 4 <= m; i += 4) {
        int4 s4 = row4[i >> 2];
        GLD(G, s4.x, r0); GLD(G, s4.y, r1); GLD(G, s4.z, r2); GLD(G, s4.w, r3);
        ACC2(acc, r0); ACC2(accB, r1); ACC2(acc, r2); ACC2(accB, r3);
    }
    const int* row = csr + (size_t)n * CAP;
    for (; i < m; ++i) {
        float2 raw = *(const float2*)(G + (size_t)row[i] * D_OUT + c);
        ACC2(acc, raw);
    }
    float di = rsqrtf((float)cn + 1.0f);
    __half2 h0 = __floats2half2_rn(di * (acc.x + accB.x) + b[c + 0],
                                   di * (acc.y + accB.y) + b[c + 1]);
    __half2 h1 = __floats2half2_rn(di * (acc.z + accB.z) + b[c + 2],
                                   di * (acc.w + accB.w) + b[c + 3]);
    float2 packed = make_float2(*(float*)&h0, *(float*)&h1);
    *(float2*)(OUT + (size_t)n * D_OUT + c) = packed;
}

// ---------------- logits: 4 thr/edge (at random-line fill floor), H fp16 [N,32] ----------------
__global__ void logits_kernel(const int* __restrict__ src, const int* __restrict__ dst,
                              const __half* __restrict__ H, float* __restrict__ out, int E) {
    long long gid = (long long)blockIdx.x * blockDim.x + threadIdx.x;
    int e = (int)(gid >> 2);
    int c = ((int)gid & 3) * 8;
    if (e >= E) return;
    int s = src[e], d = dst[e];
    float4 ra = *(const float4*)(H + (long long)s * D_OUT + c);
    float4 rb = *(const float4*)(H + (long long)d * D_OUT + c);
    __half2* pa = (__half2*)&ra;
    __half2* pb = (__half2*)&rb;
    float p = 0.f;
#pragma unroll
    for (int k = 0; k < 4; ++k) {
        float2 fa = __half22float2(pa[k]);
        float2 fb = __half22float2(pb[k]);
        p += fa.x * fb.x + fa.y * fb.y;
    }
    p += __shfl_xor(p, 1);
    p += __shfl_xor(p, 2);
    if ((gid & 3) == 0) out[e] = p;
}

extern "C" void kernel_launch(void* const* d_in, const int* in_sizes, int n_in,
                              void* d_out, int out_size, void* d_ws, size_t ws_size,
                              hipStream_t stream) {
    const float* x  = (const float*)d_in[0];
    const int* edge = (const int*)d_in[1];  // [2, E]: row0 = src, row1 = dst
    const float* W1 = (const float*)d_in[2];
    const float* b1 = (const float*)d_in[3];
    const float* W2 = (const float*)d_in[4];
    const float* b2 = (const float*)d_in[5];
    float* out = (float*)d_out;

    const int* src = edge;
    const int* dst = edge + N_EDGES;

    // workspace layout (~40.4 MB peak, aliased):
    //   gcur(256i) | cnt(N) | csr(19.2M) | bins(14.4M) | xd(6.4M)
    //   g2h(6.4M) + h2h(6.4M) alias bins (bins dead after sort_scale; 12.8 <= 14.4)
    char* ws = (char*)d_ws;
    int*    gcur = (int*)ws;                                   // 256 ints (zeroed)
    int*    cnt  = gcur + 256;                                 // N ints
    int*    csr  = cnt + N_NODES;                              // N*CAP ints (19.2 MB)
    int2*   bins = (int2*)(csr + (size_t)N_NODES * CAP);       // 250*7200*8 = 14.4 MB
    __half* xd   = (__half*)(bins + (size_t)PGROUPS * PBINCAP);// N*32 halves (6.4 MB)
    __half* g2h  = (__half*)bins;                              // alias: bins dead after sort
    __half* h2h  = g2h + (size_t)N_NODES * D_OUT;              // alias: still inside bins

    hipMemsetAsync(gcur, 0, 256 * sizeof(int), stream);

    // one coalesced edge scan -> 250 dst-range bins (196 blocks, fat tiles)
    partition_kernel<<<(N_EDGES + PTILE - 1) / PTILE, 512, 0, stream>>>(src, dst, gcur, bins, N_EDGES);

    // per-group CSR build (LDS counting, no global atomics) + fused xd = half(x*dinv)
    sort_scale_kernel<<<PGROUPS, 256, 0, stream>>>(bins, gcur, x, cnt, csr, xd);

    // fused: ax = dinv*(xd[n]+sum xd[s]); h1 = relu(ax@W1+b1); g2 = half(dinv*(h1@W2))
    agg_mlp_kernel<<<N_NODES / 32, 256, 0, stream>>>(cnt, csr, xd, W1, b1, W2, g2h, N_NODES);

    // h2 = half(dinv*(g2[n]+sum g2[s]) + b2)
    agg2_kernel<<<(N_NODES * 8) / 256, 256, 0, stream>>>(cnt, csr, g2h, b2, h2h, N_NODES);

    // per-edge logits
    logits_kernel<<<(N_EDGES * 4) / 256, 256, 0, stream>>>(src, dst, h2h, out, N_EDGES);
}